// Round 22
// baseline (294.755 us; speedup 1.0000x reference)
//
#include <hip/hip_runtime.h>

namespace {

constexpr int kB = 16;
constexpr int kM = 1024;
constexpr int kT = 4096;
constexpr int kD = 512;
constexpr int kV = 32000;

typedef __attribute__((ext_vector_type(8))) short bfrag8;
typedef __attribute__((ext_vector_type(4))) float f4acc;

__device__ __forceinline__ ushort f2bf(float f) {
  unsigned u = __float_as_uint(f);
  u += 0x7fffu + ((u >> 16) & 1u);
  return (ushort)(u >> 16);
}
__device__ __forceinline__ float bf2f(ushort h) {
  return __uint_as_float(((unsigned)h) << 16);
}

__device__ __forceinline__ void gload_lds16(const void* g, void* l) {
  __builtin_amdgcn_global_load_lds(
      (const __attribute__((address_space(1))) void*)g,
      (__attribute__((address_space(3))) void*)l, 16, 0, 0);
}

// ======== fused kernel 1 (512 thr): count(128) | prep(812) | mm2(256) =======
constexpr int kN0 = kV * kD / 4;            // emb -> EMBb
constexpr int kN1 = kN0 + 2 * kD * kD / 4;  // Ws
constexpr int kN2 = kN1 + 2 * kD * kD / 4;  // Wn
constexpr int kN3 = kN2 + kD * 1536 / 4;    // Wt
constexpr int kN4 = kN3 + kB * kM * 128;    // X0 = bf16(emb[cid])
constexpr int kCNTB = 128;                  // count: 128 x 512 = 65536 triples
constexpr int kPREPB = kN4 / 8192;          // 812 blocks x 4 chunks x 2048 f4
constexpr int kMM2B = 256;

__global__ __launch_bounds__(512) void fused_prep_k(
    const float4* __restrict__ emb, const float4* __restrict__ Ws,
    const float4* __restrict__ Wn, const float4* __restrict__ Wt,
    const float* __restrict__ Wnf, const float* __restrict__ Wtf,
    const float* __restrict__ Wrf,
    const int* __restrict__ cid,
    const int* __restrict__ headp, const int* __restrict__ tailp,
    const int* __restrict__ lblp,
    ushort4* __restrict__ EMBb, ushort4* __restrict__ Wsb,
    ushort4* __restrict__ Wnb, ushort4* __restrict__ Wtb,
    ushort4* __restrict__ X0,
    int* __restrict__ deg,
    ushort* __restrict__ Wn2r, float* __restrict__ T1)
{
  __shared__ __align__(16) float prow[4][512];  // 8 KB (mm2 branch only)
  const int bid = blockIdx.x;
  const int tid = threadIdx.x;

  if (bid < kCNTB) {
    // ---- degree count: global atomics, sharded over 128 blocks ----
    int i = bid * 512 + tid;  // 0..65535 (= kB*kT)
    if (lblp[i] != -1) {
      int b = i >> 12;
      atomicAdd(&deg[(b << 10) + tailp[i]], 1);
      atomicAdd(&deg[(b << 10) + headp[i]], 1);
    }
  } else if (bid < kCNTB + kPREPB) {
    // ---- bf16 conversions + X0 gather: persistent, 4 chunks x 4 f4/thread --
    const int bidp = bid - kCNTB;
    for (int c = 0; c < 4; ++c) {
      const int base = (bidp * 4 + c) * 2048 + tid;
      const float4* sp[4];
      ushort4* dp[4];
#pragma unroll
      for (int j = 0; j < 4; ++j) {
        int i = base + j * 512;
        if (i < kN0) { sp[j] = emb + i; dp[j] = EMBb + i; }
        else if (i < kN1) { sp[j] = Ws + (i - kN0); dp[j] = Wsb + (i - kN0); }
        else if (i < kN2) { sp[j] = Wn + (i - kN1); dp[j] = Wnb + (i - kN1); }
        else if (i < kN3) { sp[j] = Wt + (i - kN2); dp[j] = Wtb + (i - kN2); }
        else {
          int idx = i - kN3;
          sp[j] = emb + (size_t)cid[idx >> 7] * 128 + (idx & 127);
          dp[j] = X0 + idx;
        }
      }
      float4 v[4];
#pragma unroll
      for (int j = 0; j < 4; ++j) v[j] = *sp[j];
#pragma unroll
      for (int j = 0; j < 4; ++j) {
        ushort4 o;
        o.x = f2bf(v[j].x); o.y = f2bf(v[j].y);
        o.z = f2bf(v[j].z); o.w = f2bf(v[j].w);
        *dp[j] = o;
      }
    }
  } else {
    // ---- smallmm2 (K-loop unrolled x8): Wn2r = Wn2.Wr1; T1 = Wt2seg.Wr2 ----
    const int mb = bid - kCNTB - kPREPB;
    const int job = mb >> 7;
    const int e0 = (mb & 127) * 4;
    const int k = tid;
    const float* P;
    int strideP, offsP;
    const float* Q;
    if (job == 0) { P = Wnf + (size_t)kD * kD; strideP = 512; offsP = 0; Q = Wrf; }
    else { P = Wtf; strideP = 1536; offsP = 512; Q = Wrf + (size_t)kD * kD; }
#pragma unroll
    for (int i = 0; i < 4; ++i)
      prow[i][k] = P[(size_t)(e0 + i) * strideP + offsP + k];
    __syncthreads();
    float acc[4] = {0.f, 0.f, 0.f, 0.f};
    for (int a = 0; a < 512; a += 8) {
      float qv[8];
#pragma unroll
      for (int u = 0; u < 8; ++u) qv[u] = Q[(a + u) * 512 + k];
#pragma unroll
      for (int u = 0; u < 8; ++u)
#pragma unroll
        for (int i = 0; i < 4; ++i)
          acc[i] = fmaf(prow[i][a + u], qv[u], acc[i]);
    }
#pragma unroll
    for (int i = 0; i < 4; ++i) {
      if (job == 0) Wn2r[(e0 + i) * 512 + k] = f2bf(acc[i]);
      else T1[(e0 + i) * 512 + k] = acc[i];
    }
  }
}

// ---------------- CSR tail kernels (r2/r3-proven pipeline) ----------------
__global__ __launch_bounds__(1024) void scan_k(
    const int* __restrict__ deg, int* __restrict__ rowstart,
    int* __restrict__ fillptr)
{
  __shared__ int s[kM];
  int b = blockIdx.x;
  int tid = threadIdx.x;
  int d = deg[b * kM + tid];
  s[tid] = d;
  __syncthreads();
  for (int off = 1; off < kM; off <<= 1) {
    int add = (tid >= off) ? s[tid - off] : 0;
    __syncthreads();
    s[tid] += add;
    __syncthreads();
  }
  int rs = b * (2 * kT) + s[tid] - d;
  rowstart[b * kM + tid] = rs;
  fillptr[b * kM + tid] = rs;
}

// pack: (seq = 2t + isHeadEntry) << 10 | src
__global__ __launch_bounds__(256) void fill_k(
    const int* __restrict__ headp, const int* __restrict__ tailp,
    const int* __restrict__ lblp, int* __restrict__ fillptr,
    int* __restrict__ epack)
{
  int i = blockIdx.x * 256 + threadIdx.x;
  if (i >= kB * kT) return;
  if (lblp[i] == -1) return;
  int b = i >> 12;
  int t = i & (kT - 1);
  int hd = headp[i];
  int tl = tailp[i];
  int p0 = atomicAdd(&fillptr[(b << 10) + tl], 1);
  epack[p0] = ((t * 2) << 10) | hd;
  int p1 = atomicAdd(&fillptr[(b << 10) + hd], 1);
  epack[p1] = ((t * 2 + 1) << 10) | tl;
}

// per-node insertion sort by packed key -> exact reference order
__global__ __launch_bounds__(256) void sort_k(
    const int* __restrict__ rowstart, const int* __restrict__ deg,
    int* __restrict__ epack)
{
  int bm = blockIdx.x * 256 + threadIdx.x;
  if (bm >= kB * kM) return;
  int rs = rowstart[bm];
  int dg = deg[bm];
  for (int i = 1; i < dg; ++i) {
    int key = epack[rs + i];
    int j = i - 1;
    while (j >= 0 && epack[rs + j] > key) {
      epack[rs + j + 1] = epack[rs + j];
      --j;
    }
    epack[rs + j + 1] = key;
  }
}

// ======== fused kernel 2: Wfold = T1.Wr1 (128 blocks) | agg_xr (4096) =======
constexpr int kFOLDB = 128;

__global__ __launch_bounds__(512) void fold_aggxr_k(
    const float* __restrict__ T1, const float* __restrict__ Wrf,
    ushort* __restrict__ Wfold,
    const ushort4* __restrict__ Xv, const ushort4* __restrict__ EMBv,
    const int* __restrict__ relid,
    const int* __restrict__ deg, const int* __restrict__ rowstart,
    const int* __restrict__ epack,
    ushort4* __restrict__ SxC, ushort4* __restrict__ nSr0n)
{
  __shared__ float prow[4][512];
  const int bid = blockIdx.x;
  const int tid = threadIdx.x;
  if (bid < kFOLDB) {
    int e0 = bid * 4;
    int k = tid;
#pragma unroll
    for (int i = 0; i < 4; ++i)
      prow[i][k] = T1[(size_t)(e0 + i) * 512 + k];
    __syncthreads();
    float acc[4] = {0.f, 0.f, 0.f, 0.f};
    for (int a = 0; a < 512; a += 8) {
      float qv[8];
#pragma unroll
      for (int u = 0; u < 8; ++u) qv[u] = Wrf[(a + u) * 512 + k];
#pragma unroll
      for (int u = 0; u < 8; ++u)
#pragma unroll
        for (int i = 0; i < 4; ++i)
          acc[i] = fmaf(prow[i][a + u], qv[u], acc[i]);
    }
#pragma unroll
    for (int i = 0; i < 4; ++i) Wfold[(e0 + i) * 512 + k] = f2bf(acc[i]);
  } else {
    int bm = (bid - kFOLDB) * 4 + (tid >> 7);
    int t128 = tid & 127;
    int b = bm >> 10;
    int dg = deg[bm];
    int rs = rowstart[bm];
    const int* rid = relid + (b << 12);
    size_t xbase = (size_t)b * kM * 128;
    float ax = 0.f, ay = 0.f, az = 0.f, aw = 0.f;
    float rx = 0.f, ry = 0.f, rz = 0.f, rw = 0.f;
    int e = 0;
    for (; e + 4 <= dg; e += 4) {
      int pk[4];
#pragma unroll
      for (int j = 0; j < 4; ++j) pk[j] = epack[rs + e + j];
      ushort4 xv[4], rv[4];
#pragma unroll
      for (int j = 0; j < 4; ++j) {
        xv[j] = Xv[xbase + (size_t)(pk[j] & 1023) * 128 + t128];
        rv[j] = EMBv[(size_t)rid[pk[j] >> 11] * 128 + t128];
      }
#pragma unroll
      for (int j = 0; j < 4; ++j) {
        ax += bf2f(xv[j].x); ay += bf2f(xv[j].y);
        az += bf2f(xv[j].z); aw += bf2f(xv[j].w);
        rx += bf2f(rv[j].x); ry += bf2f(rv[j].y);
        rz += bf2f(rv[j].z); rw += bf2f(rv[j].w);
      }
    }
    for (; e < dg; ++e) {
      int pk = epack[rs + e];
      ushort4 xv = Xv[xbase + (size_t)(pk & 1023) * 128 + t128];
      ushort4 rv = EMBv[(size_t)rid[pk >> 11] * 128 + t128];
      ax += bf2f(xv.x); ay += bf2f(xv.y); az += bf2f(xv.z); aw += bf2f(xv.w);
      rx += bf2f(rv.x); ry += bf2f(rv.y); rz += bf2f(rv.z); rw += bf2f(rv.w);
    }
    float s = 1.0f / (float)(dg > 0 ? dg : 1);
    ushort4 o;
    o.x = f2bf((ax - rx) * s); o.y = f2bf((ay - ry) * s);
    o.z = f2bf((az - rz) * s); o.w = f2bf((aw - rw) * s);
    SxC[(size_t)bm * 128 + t128] = o;
    o.x = f2bf(-rx * s); o.y = f2bf(-ry * s);
    o.z = f2bf(-rz * s); o.w = f2bf(-rw * s);
    nSr0n[(size_t)bm * 128 + t128] = o;
  }
}

// ---------------- Sxn[bm] = (sum_edges X[src]) / max(cnt,1), unrolled x4 ------
__global__ __launch_bounds__(128) void agg_x_k(
    const ushort4* __restrict__ Xv,
    const int* __restrict__ deg, const int* __restrict__ rowstart,
    const int* __restrict__ epack, ushort4* __restrict__ outv)
{
  int bm = blockIdx.x;
  int b = bm >> 10;
  int tid = threadIdx.x;
  int dg = deg[bm];
  int rs = rowstart[bm];
  size_t xbase = (size_t)b * kM * 128;
  float ax = 0.f, ay = 0.f, az = 0.f, aw = 0.f;
  int e = 0;
  for (; e + 4 <= dg; e += 4) {
    int pk[4];
#pragma unroll
    for (int j = 0; j < 4; ++j) pk[j] = epack[rs + e + j];
    ushort4 xv[4];
#pragma unroll
    for (int j = 0; j < 4; ++j)
      xv[j] = Xv[xbase + (size_t)(pk[j] & 1023) * 128 + tid];
#pragma unroll
    for (int j = 0; j < 4; ++j) {
      ax += bf2f(xv[j].x); ay += bf2f(xv[j].y);
      az += bf2f(xv[j].z); aw += bf2f(xv[j].w);
    }
  }
  for (; e < dg; ++e) {
    int src = epack[rs + e] & 1023;
    ushort4 xv = Xv[xbase + (size_t)src * 128 + tid];
    ax += bf2f(xv.x); ay += bf2f(xv.y); az += bf2f(xv.z); aw += bf2f(xv.w);
  }
  float s = 1.0f / (float)(dg > 0 ? dg : 1);
  ushort4 o;
  o.x = f2bf(ax * s); o.y = f2bf(ay * s); o.z = f2bf(az * s); o.w = f2bf(aw * s);
  outv[(size_t)bm * 128 + tid] = o;
}

// ---------------- bf16 MFMA GEMM (128x128 tile, 2-barrier LDS loop) ----------
// MODE 0: hop2  C = relu([X|Sxn|nSr0n] @ [Ws2|Wn2|Wn2r]^T), K=1536. SWZ.
// MODE 1: hop1  C = relu([X|SxC] @ [Ws1|Wn1]^T), K=1024. SWZ.
// MODE 4: HT    C = X2 @ [Wt1|Wt3]^T (N=1024, out stride 1024). SWZ.
// MODE 5: REL2  C = EMBb @ Wfold^T (M=32000 dense). no SWZ.
template<int MODE>
__global__ __launch_bounds__(256) void gemm_k(
    const ushort* __restrict__ A0, const ushort* __restrict__ A1,
    const ushort* __restrict__ A2,
    const ushort* __restrict__ W1, const ushort* __restrict__ W2,
    const ushort* __restrict__ W3,
    ushort* __restrict__ outbf)
{
  constexpr int NSEG = (MODE == 0) ? 3 : (MODE == 1) ? 2 : 1;
  constexpr bool RELU = (MODE == 0) || (MODE == 1);
  constexpr int NC = (MODE == 4) ? 8 : 4;
  constexpr int OSTR = (MODE == 4) ? 1024 : 512;
  constexpr bool SWZ = (MODE != 5);

  __shared__ __align__(16) char lds[32768];
  char* ldsA = lds;
  char* ldsB = lds + 16384;
  const int tid = threadIdx.x;
  const int w = tid >> 6;
  const int l = tid & 63;
  const int wr = w >> 1;
  const int wc = w & 1;
  const int bid = blockIdx.x;
  int panel, col;
  if constexpr (SWZ) {
    int xcd = bid & 7;
    int idx = bid >> 3;
    panel = xcd * (((int)gridDim.x >> 3) / NC) + idx / NC;
    col = idx % NC;
  } else {
    panel = bid >> 2;
    col = bid & 3;
  }
  const int rowBase = panel * 128;
  const int colBase = col * 128;

  f4acc acc[4][4];
#pragma unroll
  for (int i = 0; i < 4; ++i)
#pragma unroll
    for (int j = 0; j < 4; ++j) acc[i][j] = (f4acc)(0.f);

  int lrow[4], gc[4];
#pragma unroll
  for (int i = 0; i < 4; ++i) {
    int P = (i * 4 + w) * 64 + l;
    lrow[i] = P >> 3;
    gc[i] = (P & 7) ^ (lrow[i] & 7);
  }

  for (int seg = 0; seg < NSEG; ++seg) {
    const char* aP[4];
    const char* bP[4];
#pragma unroll
    for (int i = 0; i < 4; ++i) {
      int grow = rowBase + lrow[i];
      const ushort* ab;
      if constexpr (MODE == 0) {
        ab = (seg == 0 ? A0 : (seg == 1 ? A1 : A2)) + (size_t)grow * kD;
      } else if constexpr (MODE == 1) {
        ab = (seg == 0 ? A0 : A1) + (size_t)grow * kD;
      } else {
        ab = A0 + (size_t)grow * kD;
      }
      aP[i] = (const char*)ab + gc[i] * 16;
      int e = colBase + lrow[i];
      const ushort* wb;
      if constexpr (MODE == 0) {
        wb = (seg == 0 ? W1 : (seg == 1 ? W2 : W3)) + (size_t)e * kD;
      } else if constexpr (MODE == 1) {
        wb = (seg == 0 ? W1 : W2) + (size_t)e * kD;
      } else if constexpr (MODE == 4) {
        wb = W1 + (size_t)(e & 511) * 1536 + (e >> 9) * 1024;
      } else {
        wb = W1 + (size_t)e * kD;
      }
      bP[i] = (const char*)wb + gc[i] * 16;
    }
    for (int kcl = 0; kcl < 8; ++kcl) {
      __syncthreads();
#pragma unroll
      for (int i = 0; i < 4; ++i) {
        gload_lds16(aP[i] + kcl * 128, ldsA + (i * 4 + w) * 1024);
        gload_lds16(bP[i] + kcl * 128, ldsB + (i * 4 + w) * 1024);
      }
      __syncthreads();
#pragma unroll
      for (int ksub = 0; ksub < 2; ++ksub) {
        bfrag8 ef[4], wf[4];
#pragma unroll
        for (int mi = 0; mi < 4; ++mi) {
          int r = wr * 64 + mi * 16 + (l & 15);
          int g = (ksub * 4 + (l >> 4)) ^ (r & 7);
          ef[mi] = *(const bfrag8*)(ldsA + r * 128 + g * 16);
        }
#pragma unroll
        for (int ni = 0; ni < 4; ++ni) {
          int e = wc * 64 + ni * 16 + (l & 15);
          int g = (ksub * 4 + (l >> 4)) ^ (e & 7);
          wf[ni] = *(const bfrag8*)(ldsB + e * 128 + g * 16);
        }
#pragma unroll
        for (int mi = 0; mi < 4; ++mi)
#pragma unroll
          for (int ni = 0; ni < 4; ++ni)
            acc[mi][ni] = __builtin_amdgcn_mfma_f32_16x16x32_bf16(
                wf[ni], ef[mi], acc[mi][ni], 0, 0, 0);
      }
    }
  }

  // epilogue (swapped layout): row = ..+(l&15); cols 4-consecutive
#pragma unroll
  for (int mi = 0; mi < 4; ++mi) {
    int rr = rowBase + wr * 64 + mi * 16 + (l & 15);
#pragma unroll
    for (int ni = 0; ni < 4; ++ni) {
      int cc0 = colBase + wc * 64 + ni * 16 + (l >> 4) * 4;
      float v0 = acc[mi][ni][0], v1 = acc[mi][ni][1];
      float v2 = acc[mi][ni][2], v3 = acc[mi][ni][3];
      if constexpr (RELU) {
        v0 = fmaxf(v0, 0.f); v1 = fmaxf(v1, 0.f);
        v2 = fmaxf(v2, 0.f); v3 = fmaxf(v3, 0.f);
      }
      ushort4 o;
      o.x = f2bf(v0); o.y = f2bf(v1); o.z = f2bf(v2); o.w = f2bf(v3);
      *(ushort4*)(outbf + (size_t)rr * OSTR + cc0) = o;
    }
  }
}

// ---------------- final gather-add: out = REL2[relid] + H[head] + T[tail] ----
__global__ __launch_bounds__(128) void final_add_k(
    const ushort4* __restrict__ REL2v, const ushort4* __restrict__ HTv,
    const int* __restrict__ relid, const int* __restrict__ headp,
    const int* __restrict__ tailp,
    float* __restrict__ outf, float* __restrict__ part)
{
  const int blk = blockIdx.x;
  const int tid = threadIdx.x;
  const int r0 = blk * 32;
  float cs0 = 0.f, cs1 = 0.f, cs2 = 0.f, cs3 = 0.f;
  for (int i = 0; i < 32; i += 8) {
    ushort4 rv[8], hv[8], tv[8];
#pragma unroll
    for (int j = 0; j < 8; ++j) {
      int r = r0 + i + j;
      int bb = r >> 12;
      rv[j] = REL2v[(size_t)relid[r] * 128 + tid];
      hv[j] = HTv[((size_t)(bb << 10) + headp[r]) * 256 + tid];
      tv[j] = HTv[((size_t)(bb << 10) + tailp[r]) * 256 + 128 + tid];
    }
#pragma unroll
    for (int j = 0; j < 8; ++j) {
      f4acc ov;
      ov[0] = bf2f(rv[j].x) + bf2f(hv[j].x) + bf2f(tv[j].x);
      ov[1] = bf2f(rv[j].y) + bf2f(hv[j].y) + bf2f(tv[j].y);
      ov[2] = bf2f(rv[j].z) + bf2f(hv[j].z) + bf2f(tv[j].z);
      ov[3] = bf2f(rv[j].w) + bf2f(hv[j].w) + bf2f(tv[j].w);
      cs0 += ov[0]; cs1 += ov[1]; cs2 += ov[2]; cs3 += ov[3];
      __builtin_nontemporal_store(
          ov, (f4acc*)(outf + (size_t)(r0 + i + j) * 512 + tid * 4));
    }
  }
  float4 o; o.x = cs0; o.y = cs1; o.z = cs2; o.w = cs3;
  *(float4*)(part + (size_t)blk * 512 + tid * 4) = o;
}

// ---------------- encoded_cause: sum 128 block partials per batch ----------
__global__ __launch_bounds__(512) void reduce_enc_k(
    const float* __restrict__ part, float* __restrict__ enc)
{
  int b = blockIdx.x;
  int c = threadIdx.x;
  float s = 0.f;
  for (int rt = 0; rt < 128; ++rt) s += part[(size_t)(b * 128 + rt) * 512 + c];
  enc[b * 512 + c] = s;
}

}  // namespace

extern "C" void kernel_launch(void* const* d_in, const int* in_sizes, int n_in,
                              void* d_out, int out_size, void* d_ws, size_t ws_size,
                              hipStream_t stream) {
  const float* emb = (const float*)d_in[0];
  const float* Ws = (const float*)d_in[1];
  const float* Wn = (const float*)d_in[2];
  const float* Wr = (const float*)d_in[3];
  const float* Wt = (const float*)d_in[4];
  const int* cid = (const int*)d_in[5];
  const int* relid = (const int*)d_in[6];
  const int* headp = (const int*)d_in[7];
  const int* tailp = (const int*)d_in[8];
  const int* lblp = (const int*)d_in[9];
  float* out = (float*)d_out;

  // ---- ws layout (peak 75 MB; EMBb slot reused for HT after EMB dies) ----
  char* wsp = (char*)d_ws;
  ushort* EMBb  = (ushort*)(wsp);                        // [0,31.25) MB
  ushort* HT    = (ushort*)(wsp);                        // [0,32) MB, after EMB dead
  ushort* REL2  = (ushort*)(wsp + (32ull << 20));        // [32,63.25) MB
  ushort* Wsb   = (ushort*)(wsp + (64ull << 20));        // 1 MB (2 hops)
  ushort* Wnb   = (ushort*)(wsp + (65ull << 20));        // 1 MB (2 hops)
  ushort* Wtb   = (ushort*)(wsp + (66ull << 20));        // 1.5 MB
  ushort* Wn2r  = (ushort*)(wsp + (67ull << 20) + (512ull << 10));  // 0.5 MB
  ushort* Wfold = (ushort*)(wsp + (68ull << 20));        // 0.5 MB
  float*  T1    = (float*)(wsp + (68ull << 20) + (512ull << 10));   // 1 MB fp32
  int* deg      = (int*)(wsp + (70ull << 20));           // 64 KB
  int* rowstart = deg + kB * kM;                         // 64 KB
  int* fillptr  = rowstart + kB * kM;                    // 64 KB
  int* epack    = fillptr + kB * kM;                     // 512 KB
  float* part   = (float*)(wsp + (71ull << 20));         // 4 MB [71,75)

  // ---- d_out scratch (dead before final_add's out write) ----
  char* outc = (char*)d_out;
  ushort* X0    = (ushort*)(outc);                   // 16 MB (X0, then X2)
  ushort* Sxn   = (ushort*)(outc + (16ull << 20));   // 16 MB (SxC / hop2 Sxn)
  ushort* nSr0n = (ushort*)(outc + (32ull << 20));   // 16 MB
  ushort* X1    = (ushort*)(outc + (48ull << 20));   // 16 MB (ping-pong)
  ushort* X2    = X0;                                // reuse X0 slot (dead)
  float* ENC = out + (size_t)kB * kT * kD;

  // 0. zero degree counters (graph-capture-safe async memset)
  hipMemsetAsync(deg, 0, (size_t)kB * kM * sizeof(int), stream);

  // 1. fused: deg count (128 blk, global atomics) | persistent prep | mm2
  fused_prep_k<<<kCNTB + kPREPB + kMM2B, 512, 0, stream>>>(
      (const float4*)emb, (const float4*)Ws, (const float4*)Wn,
      (const float4*)Wt, Wn, Wt, Wr, cid, headp, tailp, lblp,
      (ushort4*)EMBb, (ushort4*)Wsb, (ushort4*)Wnb, (ushort4*)Wtb,
      (ushort4*)X0, deg, Wn2r, T1);

  // 2-4. CSR tail: scan -> fill (global atomics) -> per-node sort
  scan_k<<<kB, 1024, 0, stream>>>(deg, rowstart, fillptr);
  fill_k<<<(kB * kT + 255) / 256, 256, 0, stream>>>(
      headp, tailp, lblp, fillptr, epack);
  sort_k<<<(kB * kM + 255) / 256, 256, 0, stream>>>(rowstart, deg, epack);

  // 5. fused: Wfold = T1.Wr1 | hop-1 aggregates (SxC combined + nSr0n)
  fold_aggxr_k<<<kFOLDB + kB * kM / 4, 512, 0, stream>>>(
      T1, Wr, Wfold, (const ushort4*)X0, (const ushort4*)EMBb, relid,
      deg, rowstart, epack, (ushort4*)Sxn, (ushort4*)nSr0n);

  // 6. hop 1 GEMM (K=1024: Wn1 segments merged) X0 -> X1
  gemm_k<1><<<(kB * kM / 128) * 4, 256, 0, stream>>>(
      X0, Sxn, nullptr, Wsb, Wnb, nullptr, X1);

  // 7. REL2 = bf16(EMB @ Wfold^T), dense vocab GEMM (last EMB reader)
  gemm_k<5><<<(kV / 128) * 4, 256, 0, stream>>>(
      EMBb, nullptr, nullptr, Wfold, nullptr, nullptr, REL2);

  // 8. hop 2 aggregate (from X1)
  agg_x_k<<<kB * kM, 128, 0, stream>>>(
      (const ushort4*)X1, deg, rowstart, epack, (ushort4*)Sxn);

  // 9. hop 2 GEMM (rel-hop folded via Wn2r) X1 -> X2
  gemm_k<0><<<(kB * kM / 128) * 4, 256, 0, stream>>>(
      X1, Sxn, nSr0n, Wsb + (size_t)kD * kD, Wnb + (size_t)kD * kD, Wn2r, X2);

  // 10. HT = X2 @ [Wt1 | Wt3]^T  (overwrites dead EMBb slot)
  gemm_k<4><<<(kB * kM / 128) * 8, 256, 0, stream>>>(
      X2, nullptr, nullptr, Wtb, nullptr, nullptr, HT);

  // 11. final gather-add stream + partials (nontemporal out stores)
  final_add_k<<<kB * kT / 32, 128, 0, stream>>>(
      (const ushort4*)REL2, (const ushort4*)HT, relid, headp, tailp, out, part);

  // 12. encoded_cause
  reduce_enc_k<<<kB, 512, 0, stream>>>(part, ENC);
}

// Round 23
// 260.426 us; speedup vs baseline: 1.1318x; 1.1318x over previous
//
#include <hip/hip_runtime.h>

namespace {

constexpr int kB = 16;
constexpr int kM = 1024;
constexpr int kT = 4096;
constexpr int kD = 512;
constexpr int kV = 32000;

typedef __attribute__((ext_vector_type(8))) short bfrag8;
typedef __attribute__((ext_vector_type(4))) float f4acc;

__device__ __forceinline__ ushort f2bf(float f) {
  unsigned u = __float_as_uint(f);
  u += 0x7fffu + ((u >> 16) & 1u);
  return (ushort)(u >> 16);
}
__device__ __forceinline__ float bf2f(ushort h) {
  return __uint_as_float(((unsigned)h) << 16);
}

__device__ __forceinline__ void gload_lds16(const void* g, void* l) {
  __builtin_amdgcn_global_load_lds(
      (const __attribute__((address_space(1))) void*)g,
      (__attribute__((address_space(3))) void*)l, 16, 0, 0);
}

// ======== fused kernel 1 (512 thr): csr(16) | prep(556 pure stream) | mm2(256)
constexpr int kN0 = kV * kD / 4;            // emb -> EMBb
constexpr int kN1 = kN0 + 2 * kD * kD / 4;  // Ws
constexpr int kN2 = kN1 + 2 * kD * kD / 4;  // Wn
constexpr int kN3 = kN2 + kD * 1536 / 4;    // Wt  (= 4,554,752; no X0 gather)
constexpr int kPREPB = kN3 / 8192;          // 556 blocks x 4 chunks x 2048 f4
constexpr int kCSRB = 16;
constexpr int kMM2B = 256;

__global__ __launch_bounds__(512) void fused_prep_k(
    const float4* __restrict__ emb, const float4* __restrict__ Ws,
    const float4* __restrict__ Wn, const float4* __restrict__ Wt,
    const float* __restrict__ Wnf, const float* __restrict__ Wtf,
    const float* __restrict__ Wrf,
    const int* __restrict__ headp, const int* __restrict__ tailp,
    const int* __restrict__ lblp,
    ushort4* __restrict__ EMBb, ushort4* __restrict__ Wsb,
    ushort4* __restrict__ Wnb, ushort4* __restrict__ Wtb,
    int* __restrict__ deg, int* __restrict__ rowstart, int* __restrict__ epack,
    ushort* __restrict__ Wn2r, float* __restrict__ T1)
{
  __shared__ __align__(16) char shm[45056];  // 44 KB (CSR branch peak)
  const int bid = blockIdx.x;
  const int tid = threadIdx.x;

  if (bid < kCSRB) {
    // ---- CSR (512 thr, 2 nodes/thread): count -> scan -> fill -> LDS sort --
    int* sdeg = (int*)shm;               // 4 KB
    int* sscan = (int*)(shm + 4096);     // 4 KB
    int* sfill = (int*)(shm + 8192);     // 4 KB
    int* sep = (int*)(shm + 12288);      // 32 KB (8192 packed entries)
    const int b = bid;
    const int n0 = tid, n1 = tid + 512;
    sdeg[n0] = 0; sdeg[n1] = 0;
    __syncthreads();
    const int* hb = headp + (b << 12);
    const int* tb = tailp + (b << 12);
    const int* lb = lblp + (b << 12);
    for (int t = tid; t < kT; t += 512) {
      if (lb[t] == -1) continue;
      atomicAdd(&sdeg[tb[t]], 1);
      atomicAdd(&sdeg[hb[t]], 1);
    }
    __syncthreads();
    int d0 = sdeg[n0], d1 = sdeg[n1];
    sscan[n0] = d0; sscan[n1] = d1;
    __syncthreads();
    for (int off = 1; off < kM; off <<= 1) {
      int v0 = (n0 >= off) ? sscan[n0 - off] : 0;
      int v1 = (n1 >= off) ? sscan[n1 - off] : 0;
      __syncthreads();
      sscan[n0] += v0; sscan[n1] += v1;
      __syncthreads();
    }
    int lrs0 = sscan[n0] - d0;
    int lrs1 = sscan[n1] - d1;
    deg[(b << 10) + n0] = d0;
    deg[(b << 10) + n1] = d1;
    rowstart[(b << 10) + n0] = b * (2 * kT) + lrs0;
    rowstart[(b << 10) + n1] = b * (2 * kT) + lrs1;
    sfill[n0] = lrs0; sfill[n1] = lrs1;
    __syncthreads();
    for (int t = tid; t < kT; t += 512) {
      if (lb[t] == -1) continue;
      int hd = hb[t];
      int tl = tb[t];
      int p0 = atomicAdd(&sfill[tl], 1);
      sep[p0] = ((t * 2) << 10) | hd;
      int p1 = atomicAdd(&sfill[hd], 1);
      sep[p1] = ((t * 2 + 1) << 10) | tl;
    }
    __syncthreads();
    // per-node insertion sort in LDS (2 nodes per thread; keys unique)
#pragma unroll
    for (int nn = 0; nn < 2; ++nn) {
      int lrs = nn ? lrs1 : lrs0;
      int d = nn ? d1 : d0;
      for (int i = 1; i < d; ++i) {
        int key = sep[lrs + i];
        int j = i - 1;
        while (j >= 0 && sep[lrs + j] > key) {
          sep[lrs + j + 1] = sep[lrs + j];
          --j;
        }
        sep[lrs + j + 1] = key;
      }
    }
    __syncthreads();
    for (int i = tid; i < 2 * kT; i += 512)
      epack[b * (2 * kT) + i] = sep[i];
  } else if (bid < kCSRB + kPREPB) {
    // ---- bf16 conversions, pure stream: 4 chunks x 4 f4/thread ----
    const int bidp = bid - kCSRB;
    for (int c = 0; c < 4; ++c) {
      const int base = (bidp * 4 + c) * 2048 + tid;
      const float4* sp[4];
      ushort4* dp[4];
#pragma unroll
      for (int j = 0; j < 4; ++j) {
        int i = base + j * 512;
        if (i < kN0) { sp[j] = emb + i; dp[j] = EMBb + i; }
        else if (i < kN1) { sp[j] = Ws + (i - kN0); dp[j] = Wsb + (i - kN0); }
        else if (i < kN2) { sp[j] = Wn + (i - kN1); dp[j] = Wnb + (i - kN1); }
        else { sp[j] = Wt + (i - kN2); dp[j] = Wtb + (i - kN2); }
      }
      float4 v[4];
#pragma unroll
      for (int j = 0; j < 4; ++j) v[j] = *sp[j];
#pragma unroll
      for (int j = 0; j < 4; ++j) {
        ushort4 o;
        o.x = f2bf(v[j].x); o.y = f2bf(v[j].y);
        o.z = f2bf(v[j].z); o.w = f2bf(v[j].w);
        *dp[j] = o;
      }
    }
  } else {
    // ---- smallmm2 (K-loop unrolled x8): Wn2r = Wn2.Wr1; T1 = Wt2seg.Wr2 ----
    float (*prow)[512] = (float(*)[512])shm;
    const int mb = bid - kCSRB - kPREPB;
    const int job = mb >> 7;
    const int e0 = (mb & 127) * 4;
    const int k = tid;
    const float* P;
    int strideP, offsP;
    const float* Q;
    if (job == 0) { P = Wnf + (size_t)kD * kD; strideP = 512; offsP = 0; Q = Wrf; }
    else { P = Wtf; strideP = 1536; offsP = 512; Q = Wrf + (size_t)kD * kD; }
#pragma unroll
    for (int i = 0; i < 4; ++i)
      prow[i][k] = P[(size_t)(e0 + i) * strideP + offsP + k];
    __syncthreads();
    float acc[4] = {0.f, 0.f, 0.f, 0.f};
    for (int a = 0; a < 512; a += 8) {
      float qv[8];
#pragma unroll
      for (int u = 0; u < 8; ++u) qv[u] = Q[(a + u) * 512 + k];
#pragma unroll
      for (int u = 0; u < 8; ++u)
#pragma unroll
        for (int i = 0; i < 4; ++i)
          acc[i] = fmaf(prow[i][a + u], qv[u], acc[i]);
    }
#pragma unroll
    for (int i = 0; i < 4; ++i) {
      if (job == 0) Wn2r[(e0 + i) * 512 + k] = f2bf(acc[i]);
      else T1[(e0 + i) * 512 + k] = acc[i];
    }
  }
}

// ======== fused kernel 2: Wfold = T1.Wr1 (128 blocks) | agg_xr (4096) =======
// agg: X0 row obtained via EMBb[cid[b,src]] (X0 never materialized).
constexpr int kFOLDB = 128;

__global__ __launch_bounds__(512) void fold_aggxr_k(
    const float* __restrict__ T1, const float* __restrict__ Wrf,
    ushort* __restrict__ Wfold,
    const int* __restrict__ cid, const ushort4* __restrict__ EMBv,
    const int* __restrict__ relid,
    const int* __restrict__ deg, const int* __restrict__ rowstart,
    const int* __restrict__ epack,
    ushort4* __restrict__ SxC, ushort4* __restrict__ nSr0n)
{
  __shared__ float prow[4][512];
  const int bid = blockIdx.x;
  const int tid = threadIdx.x;
  if (bid < kFOLDB) {
    int e0 = bid * 4;
    int k = tid;
#pragma unroll
    for (int i = 0; i < 4; ++i)
      prow[i][k] = T1[(size_t)(e0 + i) * 512 + k];
    __syncthreads();
    float acc[4] = {0.f, 0.f, 0.f, 0.f};
    for (int a = 0; a < 512; a += 8) {
      float qv[8];
#pragma unroll
      for (int u = 0; u < 8; ++u) qv[u] = Wrf[(a + u) * 512 + k];
#pragma unroll
      for (int u = 0; u < 8; ++u)
#pragma unroll
        for (int i = 0; i < 4; ++i)
          acc[i] = fmaf(prow[i][a + u], qv[u], acc[i]);
    }
#pragma unroll
    for (int i = 0; i < 4; ++i) Wfold[(e0 + i) * 512 + k] = f2bf(acc[i]);
  } else {
    int bm = (bid - kFOLDB) * 4 + (tid >> 7);
    int t128 = tid & 127;
    int b = bm >> 10;
    int dg = deg[bm];
    int rs = rowstart[bm];
    const int* rid = relid + (b << 12);
    const int* cidb = cid + (b << 10);
    float ax = 0.f, ay = 0.f, az = 0.f, aw = 0.f;
    float rx = 0.f, ry = 0.f, rz = 0.f, rw = 0.f;
    int e = 0;
    for (; e + 4 <= dg; e += 4) {
      int pk[4];
#pragma unroll
      for (int j = 0; j < 4; ++j) pk[j] = epack[rs + e + j];
      ushort4 xv[4], rv[4];
#pragma unroll
      for (int j = 0; j < 4; ++j) {
        xv[j] = EMBv[(size_t)cidb[pk[j] & 1023] * 128 + t128];
        rv[j] = EMBv[(size_t)rid[pk[j] >> 11] * 128 + t128];
      }
#pragma unroll
      for (int j = 0; j < 4; ++j) {
        ax += bf2f(xv[j].x); ay += bf2f(xv[j].y);
        az += bf2f(xv[j].z); aw += bf2f(xv[j].w);
        rx += bf2f(rv[j].x); ry += bf2f(rv[j].y);
        rz += bf2f(rv[j].z); rw += bf2f(rv[j].w);
      }
    }
    for (; e < dg; ++e) {
      int pk = epack[rs + e];
      ushort4 xv = EMBv[(size_t)cidb[pk & 1023] * 128 + t128];
      ushort4 rv = EMBv[(size_t)rid[pk >> 11] * 128 + t128];
      ax += bf2f(xv.x); ay += bf2f(xv.y); az += bf2f(xv.z); aw += bf2f(xv.w);
      rx += bf2f(rv.x); ry += bf2f(rv.y); rz += bf2f(rv.z); rw += bf2f(rv.w);
    }
    float s = 1.0f / (float)(dg > 0 ? dg : 1);
    ushort4 o;
    o.x = f2bf((ax - rx) * s); o.y = f2bf((ay - ry) * s);
    o.z = f2bf((az - rz) * s); o.w = f2bf((aw - rw) * s);
    SxC[(size_t)bm * 128 + t128] = o;
    o.x = f2bf(-rx * s); o.y = f2bf(-ry * s);
    o.z = f2bf(-rz * s); o.w = f2bf(-rw * s);
    nSr0n[(size_t)bm * 128 + t128] = o;
  }
}

// ---------------- Sxn[bm] = (sum_edges X[src]) / max(cnt,1), unrolled x4 ------
__global__ __launch_bounds__(128) void agg_x_k(
    const ushort4* __restrict__ Xv,
    const int* __restrict__ deg, const int* __restrict__ rowstart,
    const int* __restrict__ epack, ushort4* __restrict__ outv)
{
  int bm = blockIdx.x;
  int b = bm >> 10;
  int tid = threadIdx.x;
  int dg = deg[bm];
  int rs = rowstart[bm];
  size_t xbase = (size_t)b * kM * 128;
  float ax = 0.f, ay = 0.f, az = 0.f, aw = 0.f;
  int e = 0;
  for (; e + 4 <= dg; e += 4) {
    int pk[4];
#pragma unroll
    for (int j = 0; j < 4; ++j) pk[j] = epack[rs + e + j];
    ushort4 xv[4];
#pragma unroll
    for (int j = 0; j < 4; ++j)
      xv[j] = Xv[xbase + (size_t)(pk[j] & 1023) * 128 + tid];
#pragma unroll
    for (int j = 0; j < 4; ++j) {
      ax += bf2f(xv[j].x); ay += bf2f(xv[j].y);
      az += bf2f(xv[j].z); aw += bf2f(xv[j].w);
    }
  }
  for (; e < dg; ++e) {
    int src = epack[rs + e] & 1023;
    ushort4 xv = Xv[xbase + (size_t)src * 128 + tid];
    ax += bf2f(xv.x); ay += bf2f(xv.y); az += bf2f(xv.z); aw += bf2f(xv.w);
  }
  float s = 1.0f / (float)(dg > 0 ? dg : 1);
  ushort4 o;
  o.x = f2bf(ax * s); o.y = f2bf(ay * s); o.z = f2bf(az * s); o.w = f2bf(aw * s);
  outv[(size_t)bm * 128 + tid] = o;
}

// ---------------- bf16 MFMA GEMM (128x128 tile, 2-barrier LDS loop) ----------
// MODE 0: hop2  C = relu([X|Sxn|nSr0n] @ [Ws2|Wn2|Wn2r]^T), K=1536. SWZ.
// MODE 1: hop1  C = relu([EMBb[cid]|SxC] @ [Ws1|Wn1]^T), K=1024. SWZ, A-gather.
// MODE 4: HT    C = X2 @ [Wt1|Wt3]^T (N=1024, out stride 1024). SWZ.
// MODE 5: REL2  C = EMBb @ Wfold^T (M=32000 dense). no SWZ.
template<int MODE>
__global__ __launch_bounds__(256) void gemm_k(
    const ushort* __restrict__ A0, const ushort* __restrict__ A1,
    const ushort* __restrict__ A2,
    const ushort* __restrict__ W1, const ushort* __restrict__ W2,
    const ushort* __restrict__ W3,
    const int* __restrict__ cid,
    ushort* __restrict__ outbf)
{
  constexpr int NSEG = (MODE == 0) ? 3 : (MODE == 1) ? 2 : 1;
  constexpr bool RELU = (MODE == 0) || (MODE == 1);
  constexpr int NC = (MODE == 4) ? 8 : 4;
  constexpr int OSTR = (MODE == 4) ? 1024 : 512;
  constexpr bool SWZ = (MODE != 5);

  __shared__ __align__(16) char lds[32768];
  char* ldsA = lds;
  char* ldsB = lds + 16384;
  const int tid = threadIdx.x;
  const int w = tid >> 6;
  const int l = tid & 63;
  const int wr = w >> 1;
  const int wc = w & 1;
  const int bid = blockIdx.x;
  int panel, col;
  if constexpr (SWZ) {
    int xcd = bid & 7;
    int idx = bid >> 3;
    panel = xcd * (((int)gridDim.x >> 3) / NC) + idx / NC;
    col = idx % NC;
  } else {
    panel = bid >> 2;
    col = bid & 3;
  }
  const int rowBase = panel * 128;
  const int colBase = col * 128;

  f4acc acc[4][4];
#pragma unroll
  for (int i = 0; i < 4; ++i)
#pragma unroll
    for (int j = 0; j < 4; ++j) acc[i][j] = (f4acc)(0.f);

  int lrow[4], gc[4];
#pragma unroll
  for (int i = 0; i < 4; ++i) {
    int P = (i * 4 + w) * 64 + l;
    lrow[i] = P >> 3;
    gc[i] = (P & 7) ^ (lrow[i] & 7);
  }

  for (int seg = 0; seg < NSEG; ++seg) {
    const char* aP[4];
    const char* bP[4];
#pragma unroll
    for (int i = 0; i < 4; ++i) {
      int grow = rowBase + lrow[i];
      const ushort* ab;
      if constexpr (MODE == 0) {
        ab = (seg == 0 ? A0 : (seg == 1 ? A1 : A2)) + (size_t)grow * kD;
      } else if constexpr (MODE == 1) {
        ab = (seg == 0) ? (A0 + (size_t)cid[grow] * kD)
                        : (A1 + (size_t)grow * kD);
      } else {
        ab = A0 + (size_t)grow * kD;
      }
      aP[i] = (const char*)ab + gc[i] * 16;
      int e = colBase + lrow[i];
      const ushort* wb;
      if constexpr (MODE == 0) {
        wb = (seg == 0 ? W1 : (seg == 1 ? W2 : W3)) + (size_t)e * kD;
      } else if constexpr (MODE == 1) {
        wb = (seg == 0 ? W1 : W2) + (size_t)e * kD;
      } else if constexpr (MODE == 4) {
        wb = W1 + (size_t)(e & 511) * 1536 + (e >> 9) * 1024;
      } else {
        wb = W1 + (size_t)e * kD;
      }
      bP[i] = (const char*)wb + gc[i] * 16;
    }
    for (int kcl = 0; kcl < 8; ++kcl) {
      __syncthreads();
#pragma unroll
      for (int i = 0; i < 4; ++i) {
        gload_lds16(aP[i] + kcl * 128, ldsA + (i * 4 + w) * 1024);
        gload_lds16(bP[i] + kcl * 128, ldsB + (i * 4 + w) * 1024);
      }
      __syncthreads();
#pragma unroll
      for (int ksub = 0; ksub < 2; ++ksub) {
        bfrag8 ef[4], wf[4];
#pragma unroll
        for (int mi = 0; mi < 4; ++mi) {
          int r = wr * 64 + mi * 16 + (l & 15);
          int g = (ksub * 4 + (l >> 4)) ^ (r & 7);
          ef[mi] = *(const bfrag8*)(ldsA + r * 128 + g * 16);
        }
#pragma unroll
        for (int ni = 0; ni < 4; ++ni) {
          int e = wc * 64 + ni * 16 + (l & 15);
          int g = (ksub * 4 + (l >> 4)) ^ (e & 7);
          wf[ni] = *(const bfrag8*)(ldsB + e * 128 + g * 16);
        }
#pragma unroll
        for (int mi = 0; mi < 4; ++mi)
#pragma unroll
          for (int ni = 0; ni < 4; ++ni)
            acc[mi][ni] = __builtin_amdgcn_mfma_f32_16x16x32_bf16(
                wf[ni], ef[mi], acc[mi][ni], 0, 0, 0);
      }
    }
  }

  // epilogue (swapped layout): row = ..+(l&15); cols 4-consecutive
#pragma unroll
  for (int mi = 0; mi < 4; ++mi) {
    int rr = rowBase + wr * 64 + mi * 16 + (l & 15);
#pragma unroll
    for (int ni = 0; ni < 4; ++ni) {
      int cc0 = colBase + wc * 64 + ni * 16 + (l >> 4) * 4;
      float v0 = acc[mi][ni][0], v1 = acc[mi][ni][1];
      float v2 = acc[mi][ni][2], v3 = acc[mi][ni][3];
      if constexpr (RELU) {
        v0 = fmaxf(v0, 0.f); v1 = fmaxf(v1, 0.f);
        v2 = fmaxf(v2, 0.f); v3 = fmaxf(v3, 0.f);
      }
      ushort4 o;
      o.x = f2bf(v0); o.y = f2bf(v1); o.z = f2bf(v2); o.w = f2bf(v3);
      *(ushort4*)(outbf + (size_t)rr * OSTR + cc0) = o;
    }
  }
}

// ---------------- final gather-add: out = REL2[relid] + H[head] + T[tail] ----
__global__ __launch_bounds__(128) void final_add_k(
    const ushort4* __restrict__ REL2v, const ushort4* __restrict__ HTv,
    const int* __restrict__ relid, const int* __restrict__ headp,
    const int* __restrict__ tailp,
    float* __restrict__ outf, float* __restrict__ part)
{
  const int blk = blockIdx.x;
  const int tid = threadIdx.x;
  const int r0 = blk * 32;
  float cs0 = 0.f, cs1 = 0.f, cs2 = 0.f, cs3 = 0.f;
  for (int i = 0; i < 32; i += 8) {
    ushort4 rv[8], hv[8], tv[8];
#pragma unroll
    for (int j = 0; j < 8; ++j) {
      int r = r0 + i + j;
      int bb = r >> 12;
      rv[j] = REL2v[(size_t)relid[r] * 128 + tid];
      hv[j] = HTv[((size_t)(bb << 10) + headp[r]) * 256 + tid];
      tv[j] = HTv[((size_t)(bb << 10) + tailp[r]) * 256 + 128 + tid];
    }
#pragma unroll
    for (int j = 0; j < 8; ++j) {
      f4acc ov;
      ov[0] = bf2f(rv[j].x) + bf2f(hv[j].x) + bf2f(tv[j].x);
      ov[1] = bf2f(rv[j].y) + bf2f(hv[j].y) + bf2f(tv[j].y);
      ov[2] = bf2f(rv[j].z) + bf2f(hv[j].z) + bf2f(tv[j].z);
      ov[3] = bf2f(rv[j].w) + bf2f(hv[j].w) + bf2f(tv[j].w);
      cs0 += ov[0]; cs1 += ov[1]; cs2 += ov[2]; cs3 += ov[3];
      __builtin_nontemporal_store(
          ov, (f4acc*)(outf + (size_t)(r0 + i + j) * 512 + tid * 4));
    }
  }
  float4 o; o.x = cs0; o.y = cs1; o.z = cs2; o.w = cs3;
  *(float4*)(part + (size_t)blk * 512 + tid * 4) = o;
}

// ---------------- encoded_cause: sum 128 block partials per batch ----------
__global__ __launch_bounds__(512) void reduce_enc_k(
    const float* __restrict__ part, float* __restrict__ enc)
{
  int b = blockIdx.x;
  int c = threadIdx.x;
  float s = 0.f;
  for (int rt = 0; rt < 128; ++rt) s += part[(size_t)(b * 128 + rt) * 512 + c];
  enc[b * 512 + c] = s;
}

}  // namespace

extern "C" void kernel_launch(void* const* d_in, const int* in_sizes, int n_in,
                              void* d_out, int out_size, void* d_ws, size_t ws_size,
                              hipStream_t stream) {
  const float* emb = (const float*)d_in[0];
  const float* Ws = (const float*)d_in[1];
  const float* Wn = (const float*)d_in[2];
  const float* Wr = (const float*)d_in[3];
  const float* Wt = (const float*)d_in[4];
  const int* cid = (const int*)d_in[5];
  const int* relid = (const int*)d_in[6];
  const int* headp = (const int*)d_in[7];
  const int* tailp = (const int*)d_in[8];
  const int* lblp = (const int*)d_in[9];
  float* out = (float*)d_out;

  // ---- ws layout (peak 75 MB; EMBb slot reused for HT after EMB dies) ----
  char* wsp = (char*)d_ws;
  ushort* EMBb  = (ushort*)(wsp);                        // [0,31.25) MB
  ushort* HT    = (ushort*)(wsp);                        // [0,32) MB, after EMB dead
  ushort* REL2  = (ushort*)(wsp + (32ull << 20));        // [32,63.25) MB
  ushort* Wsb   = (ushort*)(wsp + (64ull << 20));        // 1 MB (2 hops)
  ushort* Wnb   = (ushort*)(wsp + (65ull << 20));        // 1 MB (2 hops)
  ushort* Wtb   = (ushort*)(wsp + (66ull << 20));        // 1.5 MB
  ushort* Wn2r  = (ushort*)(wsp + (67ull << 20) + (512ull << 10));  // 0.5 MB
  ushort* Wfold = (ushort*)(wsp + (68ull << 20));        // 0.5 MB
  float*  T1    = (float*)(wsp + (68ull << 20) + (512ull << 10));   // 1 MB fp32
  int* deg      = (int*)(wsp + (70ull << 20));           // 64 KB
  int* rowstart = deg + kB * kM;                         // 64 KB
  int* epack    = rowstart + kB * kM;                    // 512 KB
  float* part   = (float*)(wsp + (71ull << 20));         // 4 MB [71,75)

  // ---- d_out scratch (dead before final_add's out write) ----
  char* outc = (char*)d_out;
  ushort* X2    = (ushort*)(outc);                   // 16 MB
  ushort* Sxn   = (ushort*)(outc + (16ull << 20));   // 16 MB (SxC / hop2 Sxn)
  ushort* nSr0n = (ushort*)(outc + (32ull << 20));   // 16 MB
  ushort* X1    = (ushort*)(outc + (48ull << 20));   // 16 MB
  float* ENC = out + (size_t)kB * kT * kD;

  // 1. fused: csr (LDS sort) | pure-stream bf16 conversions | {Wn2r,T1} folds
  fused_prep_k<<<kCSRB + kPREPB + kMM2B, 512, 0, stream>>>(
      (const float4*)emb, (const float4*)Ws, (const float4*)Wn,
      (const float4*)Wt, Wn, Wt, Wr, headp, tailp, lblp,
      (ushort4*)EMBb, (ushort4*)Wsb, (ushort4*)Wnb, (ushort4*)Wtb,
      deg, rowstart, epack, Wn2r, T1);

  // 2. fused: Wfold = T1.Wr1 | hop-1 aggregates (X0 via EMBb[cid] indirection)
  fold_aggxr_k<<<kFOLDB + kB * kM / 4, 512, 0, stream>>>(
      T1, Wr, Wfold, cid, (const ushort4*)EMBb, relid,
      deg, rowstart, epack, (ushort4*)Sxn, (ushort4*)nSr0n);

  // 3. hop 1 GEMM (A-rows gathered from EMBb via cid) -> X1
  gemm_k<1><<<(kB * kM / 128) * 4, 256, 0, stream>>>(
      EMBb, Sxn, nullptr, Wsb, Wnb, nullptr, cid, X1);

  // 4. REL2 = bf16(EMB @ Wfold^T), dense vocab GEMM
  gemm_k<5><<<(kV / 128) * 4, 256, 0, stream>>>(
      EMBb, nullptr, nullptr, Wfold, nullptr, nullptr, nullptr, REL2);

  // 5. hop 2 aggregate (from X1)
  agg_x_k<<<kB * kM, 128, 0, stream>>>(
      (const ushort4*)X1, deg, rowstart, epack, (ushort4*)Sxn);

  // 6. hop 2 GEMM (rel-hop folded via Wn2r) X1 -> X2
  gemm_k<0><<<(kB * kM / 128) * 4, 256, 0, stream>>>(
      X1, Sxn, nSr0n, Wsb + (size_t)kD * kD, Wnb + (size_t)kD * kD, Wn2r,
      nullptr, X2);

  // 7. HT = X2 @ [Wt1 | Wt3]^T  (overwrites dead EMBb slot)
  gemm_k<4><<<(kB * kM / 128) * 8, 256, 0, stream>>>(
      X2, nullptr, nullptr, Wtb, nullptr, nullptr, nullptr, HT);

  // 8. final gather-add stream + partials (nontemporal out stores)
  final_add_k<<<kB * kT / 32, 128, 0, stream>>>(
      (const ushort4*)REL2, (const ushort4*)HT, relid, headp, tailp, out, part);

  // 9. encoded_cause
  reduce_enc_k<<<kB, 512, 0, stream>>>(part, ENC);
}